// Round 2
// baseline (427.651 us; speedup 1.0000x reference)
//
#include <hip/hip_runtime.h>

// Problem constants: N=4194304, C=16, G=8
#define N_ELEMS 4194304
#define C_DIM 16
#define G_NUM 8

#define BLOCKS 2048
#define TPB 256
#define NTHREADS (BLOCKS * TPB)      // 524288
#define NCLIQUES (NTHREADS / 4)      // 131072 cliques of 4 lanes; one row per clique per iter
#define ITERS (N_ELEMS / NCLIQUES)   // 32

// native clang vector type — __builtin_nontemporal_load accepts this (HIP float4 is a struct)
typedef float vfloat4 __attribute__((ext_vector_type(4)));

// ws layout: float part[BLOCKS][16] — [0..7]=sums, [8..15]=counts. 128 KB, every slot
// written unconditionally -> no memset needed despite 0xAA poisoning.

__global__ __launch_bounds__(TPB) void berl_partial(
    const float* __restrict__ input_,
    const int*   __restrict__ target,
    const int*   __restrict__ group,
    float*       __restrict__ part)
{
    const int tid   = threadIdx.x;
    const int lane  = tid & 3;                          // which 16B chunk of the 64B row
    const int gcliq = (blockIdx.x * TPB + tid) >> 2;    // global clique id

    float sums[G_NUM];
    float cnts[G_NUM];
#pragma unroll
    for (int k = 0; k < G_NUM; ++k) { sums[k] = 0.0f; cnts[k] = 0.0f; }

    const vfloat4* in4 = (const vfloat4*)input_;

#pragma unroll 4
    for (int it = 0; it < ITERS; ++it) {
        const int row = gcliq + it * NCLIQUES;
        // coalesced: a wave's 64 lanes cover 16 consecutive rows x 64B = 1KB contiguous
        vfloat4 v = __builtin_nontemporal_load(&in4[row * 4 + lane]);
        const int t = target[row];   // 4 lanes read same addr (broadcast-merged)
        const int g = group[row];

        // select component (t&3) of this lane's float4
        const int e2 = t & 3;
        float x = v.x;
        x = (e2 == 1) ? v.y : x;
        x = (e2 == 2) ? v.z : x;
        x = (e2 == 3) ? v.w : x;

        // exactly one lane of the clique owns the target element
        const bool own = ((t >> 2) == lane);
        const float e  = own ? fabsf(1.0f - x) : 0.0f;
        const float c1 = own ? 1.0f : 0.0f;

#pragma unroll
        for (int k = 0; k < G_NUM; ++k) {
            sums[k] += (g == k) ? e  : 0.0f;
            cnts[k] += (g == k) ? c1 : 0.0f;
        }
    }

    // thread -> block (LDS atomics), block -> per-block workspace slot (no global atomics)
    __shared__ float s_sums[G_NUM];
    __shared__ float s_cnts[G_NUM];
    if (tid < G_NUM) { s_sums[tid] = 0.0f; s_cnts[tid] = 0.0f; }
    __syncthreads();
#pragma unroll
    for (int k = 0; k < G_NUM; ++k) {
        atomicAdd(&s_sums[k], sums[k]);
        atomicAdd(&s_cnts[k], cnts[k]);
    }
    __syncthreads();
    if (tid < G_NUM)            part[blockIdx.x * 16 + tid] = s_sums[tid];
    else if (tid < 2 * G_NUM)   part[blockIdx.x * 16 + tid] = s_cnts[tid - G_NUM];
}

__global__ __launch_bounds__(256) void berl_final(
    const float* __restrict__ part,
    float*       __restrict__ out)
{
    __shared__ float s_acc[256];
    __shared__ float s_tot[16];
    const int tid = threadIdx.x;
    const int j   = tid & 15;   // which of the 16 columns (8 sums + 8 counts)
    const int b0  = tid >> 4;   // block-chunk

    float acc = 0.0f;
    for (int k = 0; k < BLOCKS / 16; ++k)          // 128 coalesced passes over part[2048][16]
        acc += part[(b0 + 16 * k) * 16 + j];
    s_acc[tid] = acc;
    __syncthreads();

    if (tid < 16) {
        float tot = 0.0f;
#pragma unroll
        for (int r = 0; r < 16; ++r) tot += s_acc[r * 16 + tid];
        s_tot[tid] = tot;
    }
    __syncthreads();

    if (tid == 0) {
        float acc2 = 0.0f;
#pragma unroll
        for (int g = 0; g < G_NUM; ++g) {
            const float c = s_tot[8 + g];
            const float m = (c > 0.0f) ? (s_tot[g] / fmaxf(c, 1.0f)) : 0.0f;
            acc2 += m;
        }
        out[0] = fabsf(0.5f - acc2 / (float)G_NUM);
    }
}

extern "C" void kernel_launch(void* const* d_in, const int* in_sizes, int n_in,
                              void* d_out, int out_size, void* d_ws, size_t ws_size,
                              hipStream_t stream) {
    const float* input_ = (const float*)d_in[0];
    const int*   target = (const int*)d_in[1];
    const int*   group  = (const int*)d_in[2];
    float* out  = (float*)d_out;
    float* part = (float*)d_ws;   // 2048*16 floats = 128 KB

    dim3 block(TPB);
    dim3 grid(BLOCKS);
    berl_partial<<<grid, block, 0, stream>>>(input_, target, group, part);
    berl_final<<<1, 256, 0, stream>>>(part, out);
}

// Round 4
// 408.528 us; speedup vs baseline: 1.0468x; 1.0468x over previous
//
#include <hip/hip_runtime.h>

// Problem constants: N=4194304, C=16, G=8
#define N_ELEMS 4194304
#define C_DIM 16
#define G_NUM 8

#define BLOCKS 2048
#define TPB 256

// ws layout: float part[BLOCKS][16] — [0..7]=sums, [8..15]=counts. 128 KB, every slot
// written unconditionally -> no memset needed despite 0xAA poisoning, no global atomics.

__global__ __launch_bounds__(TPB) void berl_partial(
    const float* __restrict__ input_,
    const int*   __restrict__ target,
    const int*   __restrict__ group,
    float*       __restrict__ part)
{
    const int tid = threadIdx.x;

    // per-thread register accumulators (branchless select, no LDS contention)
    float sums[G_NUM];
    float cnts[G_NUM];
#pragma unroll
    for (int g = 0; g < G_NUM; ++g) { sums[g] = 0.0f; cnts[g] = 0.0f; }

    const int4* t4 = (const int4*)target;
    const int4* g4 = (const int4*)group;
    const int n4     = N_ELEMS / 4;
    const int stride = gridDim.x * blockDim.x;

    for (int i = blockIdx.x * blockDim.x + tid; i < n4; i += stride) {
        int4 t = t4[i];
        int4 g = g4[i];
        const int base = i * (4 * C_DIM);
        float e0 = fabsf(1.0f - __builtin_nontemporal_load(&input_[base + 0 * C_DIM + t.x]));
        float e1 = fabsf(1.0f - __builtin_nontemporal_load(&input_[base + 1 * C_DIM + t.y]));
        float e2 = fabsf(1.0f - __builtin_nontemporal_load(&input_[base + 2 * C_DIM + t.z]));
        float e3 = fabsf(1.0f - __builtin_nontemporal_load(&input_[base + 3 * C_DIM + t.w]));
#pragma unroll
        for (int k = 0; k < G_NUM; ++k) {
            sums[k] += (g.x == k) ? e0 : 0.0f;
            sums[k] += (g.y == k) ? e1 : 0.0f;
            sums[k] += (g.z == k) ? e2 : 0.0f;
            sums[k] += (g.w == k) ? e3 : 0.0f;
            cnts[k] += (g.x == k) ? 1.0f : 0.0f;
            cnts[k] += (g.y == k) ? 1.0f : 0.0f;
            cnts[k] += (g.z == k) ? 1.0f : 0.0f;
            cnts[k] += (g.w == k) ? 1.0f : 0.0f;
        }
    }

    // thread -> block (LDS atomics: 16 per thread)
    __shared__ float s_sums[G_NUM];
    __shared__ float s_cnts[G_NUM];
    if (tid < G_NUM) { s_sums[tid] = 0.0f; s_cnts[tid] = 0.0f; }
    __syncthreads();
#pragma unroll
    for (int k = 0; k < G_NUM; ++k) {
        atomicAdd(&s_sums[k], sums[k]);
        atomicAdd(&s_cnts[k], cnts[k]);
    }
    __syncthreads();

    // block -> per-block workspace slot (plain coalesced stores, no init required)
    if (tid < G_NUM)            part[blockIdx.x * 16 + tid] = s_sums[tid];
    else if (tid < 2 * G_NUM)   part[blockIdx.x * 16 + tid] = s_cnts[tid - G_NUM];
}

__global__ __launch_bounds__(256) void berl_final(
    const float* __restrict__ part,
    float*       __restrict__ out)
{
    __shared__ float s_acc[256];
    __shared__ float s_tot[16];
    const int tid = threadIdx.x;
    const int j   = tid & 15;   // which of the 16 columns (8 sums + 8 counts)
    const int b0  = tid >> 4;   // block-chunk

    float acc = 0.0f;
    for (int k = 0; k < BLOCKS / 16; ++k)          // coalesced passes over part[2048][16]
        acc += part[(b0 + 16 * k) * 16 + j];
    s_acc[tid] = acc;
    __syncthreads();

    if (tid < 16) {
        float tot = 0.0f;
#pragma unroll
        for (int r = 0; r < 16; ++r) tot += s_acc[r * 16 + tid];
        s_tot[tid] = tot;
    }
    __syncthreads();

    if (tid == 0) {
        float acc2 = 0.0f;
#pragma unroll
        for (int g = 0; g < G_NUM; ++g) {
            const float c = s_tot[8 + g];
            const float m = (c > 0.0f) ? (s_tot[g] / fmaxf(c, 1.0f)) : 0.0f;
            acc2 += m;
        }
        out[0] = fabsf(0.5f - acc2 / (float)G_NUM);
    }
}

extern "C" void kernel_launch(void* const* d_in, const int* in_sizes, int n_in,
                              void* d_out, int out_size, void* d_ws, size_t ws_size,
                              hipStream_t stream) {
    const float* input_ = (const float*)d_in[0];
    const int*   target = (const int*)d_in[1];
    const int*   group  = (const int*)d_in[2];
    float* out  = (float*)d_out;
    float* part = (float*)d_ws;   // 2048*16 floats = 128 KB

    dim3 block(TPB);
    dim3 grid(BLOCKS);
    berl_partial<<<grid, block, 0, stream>>>(input_, target, group, part);
    berl_final<<<1, 256, 0, stream>>>(part, out);
}